// Round 5
// baseline (28.816 us; speedup 1.0000x reference)
//
#include <hip/hip_runtime.h>
#include <hip/hip_bf16.h>

typedef __bf16 bf16_t;
typedef __bf16 bf16x4 __attribute__((ext_vector_type(4)));
typedef __bf16 bf16x8 __attribute__((ext_vector_type(8)));
typedef float  f32x4  __attribute__((ext_vector_type(4)));

typedef __attribute__((address_space(1))) const void  gvoid_t;
typedef __attribute__((address_space(3))) void        lvoid_t;

static constexpr int Mtot = 4096;   // B*S
static constexpr int Ntot = 1024;   // H*A
static constexpr int Ktot = 1024;   // F

// out[b,s,h,a] = sum_f value_input[b,s,f] * v_w[h,f,a]
// (reference softmax over q integrates to exactly 1 in the final q-contraction)

// ============================================================================
// Prepass (W only): Wt = bf16 transpose of W: [n=h*64+a][k]  (6 MB traffic)
// ============================================================================
__global__ __launch_bounds__(256)
void prepass_w_kernel(const float* __restrict__ W, bf16_t* __restrict__ Wt)
{
    __shared__ float wtile[64][65];
    const int wb = blockIdx.x, t = threadIdx.x;
    const int head = wb >> 4;         // 0..15
    const int k0 = (wb & 15) * 64;
    const float* wsrc = W + (size_t)head * (Ktot * 64) + (size_t)k0 * 64;
#pragma unroll
    for (int i = 0; i < 4; ++i) {
        const int idx = i * 256 + t;
        const int kr = idx >> 4, a4 = (idx & 15) * 4;
        const f32x4 v = *(const f32x4*)(wsrc + (size_t)kr * 64 + a4);
        wtile[kr][a4 + 0] = v[0]; wtile[kr][a4 + 1] = v[1];
        wtile[kr][a4 + 2] = v[2]; wtile[kr][a4 + 3] = v[3];
    }
    __syncthreads();
#pragma unroll
    for (int i = 0; i < 4; ++i) {
        const int idx = i * 256 + t;
        const int ar = idx >> 4, kc = (idx & 15) * 4;
        bf16x4 p = {(bf16_t)wtile[kc + 0][ar], (bf16_t)wtile[kc + 1][ar],
                    (bf16_t)wtile[kc + 2][ar], (bf16_t)wtile[kc + 3][ar]};
        *(bf16x4*)(Wt + (size_t)(head * 64 + ar) * Ktot + k0 + kc) = p;
    }
}

// ============================================================================
// GEMM: C[4096][1024] f32 = fp32 A x bf16 Wt^T.
// A staged fp32 via global_load_lds (cvt to bf16 post-ds_read); B staged bf16.
// BM=64 BN=128 BK=64, 4 waves (2x2), grid 512 = 2 blocks/CU, LDS 64 KB.
// T2 XOR-swizzle both operands (rule #21: linear LDS dest, permuted source,
// same XOR on read). T4 counted-vmcnt loop: raw s_barrier, vmcnt(8) never 0
// in steady state -> next tile's 8 loads stay in flight across the barrier.
// ============================================================================
__global__ __launch_bounds__(256, 2)
void gemm_mixed_kernel(const float* __restrict__ A, const bf16_t* __restrict__ Bt,
                       float* __restrict__ C)
{
    __shared__ float  As[2][64 * 64];    // fp32 [row][64k], rows 256B
    __shared__ bf16_t Bs[2][128 * 64];   // bf16 [col][64k], rows 128B

    const int t = threadIdx.x, lane = t & 63, wave = t >> 6;
    const int wm = wave & 1, wn = wave >> 1;

    // XCD swizzle: 512 wgs; XCD x owns 8 M-panels x all 8 N
    const int g = (blockIdx.x & 7) * 64 + (blockIdx.x >> 3);
    const int by = g >> 3, bx = g & 7;
    const int bm = by * 64, bn = bx * 128;

    const int lrow = lane & 15;
    const int lq   = lane >> 4;          // quarter-wave 0..3

    f32x4 acc[2][4];
#pragma unroll
    for (int mf = 0; mf < 2; ++mf)
#pragma unroll
        for (int nf = 0; nf < 4; ++nf) {
            f32x4 z = {0.f, 0.f, 0.f, 0.f};
            acc[mf][nf] = z;
        }

    // 8 global_load_lds per thread (and per wave-instruction count) per STAGE
    auto STAGE = [&](int buf, int k0) {
        // A: 64 rows x 16 chunks(16B=4 fp32) = 1024 chunks, 4/thread
#pragma unroll
        for (int j = 0; j < 4; ++j) {
            const int chunk = (wave * 4 + j) * 64 + lane;
            const int row = chunk >> 4;
            const int kc  = ((chunk & 15) ^ (row & 7)) << 2;   // swizzled src col (floats)
            const float* gp = A + (size_t)(bm + row) * Ktot + k0 + kc;
            __builtin_amdgcn_global_load_lds((gvoid_t*)gp,
                (lvoid_t*)&As[buf][(wave * 4 + j) * 256], 16, 0, 0);
        }
        // B: 128 rows x 8 chunks(16B=8 bf16) = 1024 chunks, 4/thread
#pragma unroll
        for (int j = 0; j < 4; ++j) {
            const int chunk = (wave * 4 + j) * 64 + lane;
            const int row = chunk >> 3;
            const int kb  = ((chunk & 7) ^ (row & 7)) << 3;
            const bf16_t* gp = Bt + (size_t)(bn + row) * Ktot + k0 + kb;
            __builtin_amdgcn_global_load_lds((gvoid_t*)gp,
                (lvoid_t*)&Bs[buf][(wave * 4 + j) * 512], 16, 0, 0);
        }
    };

    auto COMPUTE = [&](int cur) {
#pragma unroll
        for (int kk = 0; kk < 2; ++kk) {
            const int c16 = kk * 4 + lq;          // B 16B-column 0..7
            const int gA  = kk * 8 + lq * 2;      // A even 16B-chunk 0..14
            bf16x8 af[2], bfr[4];
#pragma unroll
            for (int mf = 0; mf < 2; ++mf) {
                const int R = wm * 32 + mf * 16 + lrow;
                const int x = R & 7;
                const f32x4 lo = *(const f32x4*)&As[cur][R * 64 + ((gA ^ x) << 2)];
                const f32x4 hi = *(const f32x4*)&As[cur][R * 64 + (((gA + 1) ^ x) << 2)];
                bf16x8 v = {(bf16_t)lo[0], (bf16_t)lo[1], (bf16_t)lo[2], (bf16_t)lo[3],
                            (bf16_t)hi[0], (bf16_t)hi[1], (bf16_t)hi[2], (bf16_t)hi[3]};
                af[mf] = v;
            }
#pragma unroll
            for (int nf = 0; nf < 4; ++nf) {
                const int R = wn * 64 + nf * 16 + lrow;
                bfr[nf] = *(const bf16x8*)&Bs[cur][R * 64 + ((c16 ^ (R & 7)) << 3)];
            }
            __builtin_amdgcn_s_setprio(1);
#pragma unroll
            for (int mf = 0; mf < 2; ++mf)
#pragma unroll
                for (int nf = 0; nf < 4; ++nf)
                    acc[mf][nf] = __builtin_amdgcn_mfma_f32_16x16x32_bf16(
                        af[mf], bfr[nf], acc[mf][nf], 0, 0, 0);
            __builtin_amdgcn_s_setprio(0);
        }
    };

    constexpr int NT = Ktot / 64;   // 16
    STAGE(0, 0);                    // 8 outstanding

    for (int tI = 0; tI < NT - 1; ++tI) {
        const int cur = tI & 1;
        // barA: all waves finished reading buf cur^1 (iter tI-1's compute)
        __builtin_amdgcn_s_barrier();
        STAGE(cur ^ 1, (tI + 1) * 64);              // 16 outstanding
        asm volatile("s_waitcnt vmcnt(8)" ::: "memory");   // tile tI's 8 done
        __builtin_amdgcn_sched_barrier(0);
        __builtin_amdgcn_s_barrier();               // barB: everyone's tile-tI data landed
        __builtin_amdgcn_sched_barrier(0);
        COMPUTE(cur);
    }
    // tail: tile NT-1
    asm volatile("s_waitcnt vmcnt(0)" ::: "memory");
    __builtin_amdgcn_sched_barrier(0);
    __builtin_amdgcn_s_barrier();
    __builtin_amdgcn_sched_barrier(0);
    COMPUTE((NT - 1) & 1);

    // epilogue: C/D layout col = lane&15, row = (lane>>4)*4 + i
#pragma unroll
    for (int mf = 0; mf < 2; ++mf) {
        const int row0 = bm + wm * 32 + mf * 16 + (lq << 2);
#pragma unroll
        for (int nf = 0; nf < 4; ++nf) {
            const int col = bn + wn * 64 + nf * 16 + lrow;
#pragma unroll
            for (int i = 0; i < 4; ++i)
                C[(size_t)(row0 + i) * Ntot + col] = acc[mf][nf][i];
        }
    }
}

// ============================================================================
// Fallback (ws too small): round-2 fused kernel (proven correct, ~33 us)
// ============================================================================
static constexpr int FBM = 128, FBN = 128, FBK = 64, FBKP = 72;

__global__ __launch_bounds__(512, 2)
void vproj_fused_kernel(const float* __restrict__ A, const float* __restrict__ W,
                        float* __restrict__ C)
{
    __shared__ bf16_t As[2][FBM][FBKP];
    __shared__ bf16_t Bs[2][FBN][FBKP];

    const int t = threadIdx.x, lane = t & 63, wave = t >> 6;
    const int wm = wave >> 2, wn = wave & 3;
    const int tile = (blockIdx.x & 7) * 32 + (blockIdx.x >> 3);
    const int bm = (tile >> 3) * FBM, bn = (tile & 7) * FBN;

    const int bhead = t >> 8, brem = t & 255;
    const int bkq = brem >> 4, baq = brem & 15;
    const float* const wbase = W + ((size_t)((bn >> 6) + bhead)) * (Ktot * 64)
                                 + (size_t)(bkq * 4) * 64 + baq * 4;
    f32x4 avreg[4], bvreg[4];

    auto load_tile = [&](int k0) {
#pragma unroll
        for (int r = 0; r < 4; ++r) {
            const int idx = r * 512 + t;
            avreg[r] = *(const f32x4*)(A + (size_t)(bm + (idx >> 4)) * Ktot + k0 + (idx & 15) * 4);
        }
        const float* wp = wbase + (size_t)k0 * 64;
#pragma unroll
        for (int r = 0; r < 4; ++r) bvreg[r] = *(const f32x4*)(wp + r * 64);
    };
    auto store_tile = [&](int buf) {
#pragma unroll
        for (int r = 0; r < 4; ++r) {
            const int idx = r * 512 + t;
            bf16x4 p = {(bf16_t)avreg[r][0], (bf16_t)avreg[r][1],
                        (bf16_t)avreg[r][2], (bf16_t)avreg[r][3]};
            *(bf16x4*)&As[buf][idx >> 4][(idx & 15) * 4] = p;
        }
#pragma unroll
        for (int j = 0; j < 4; ++j) {
            bf16x4 p = {(bf16_t)bvreg[0][j], (bf16_t)bvreg[1][j],
                        (bf16_t)bvreg[2][j], (bf16_t)bvreg[3][j]};
            *(bf16x4*)&Bs[buf][bhead * 64 + baq * 4 + j][bkq * 4] = p;
        }
    };

    f32x4 acc[4][2];
#pragma unroll
    for (int mf = 0; mf < 4; ++mf)
#pragma unroll
        for (int nf = 0; nf < 2; ++nf) { f32x4 z = {0,0,0,0}; acc[mf][nf] = z; }

    const int lrow = lane & 15, lkb = (lane >> 4) << 3;
    load_tile(0); store_tile(0); __syncthreads();

    for (int tI = 0; tI < Ktot / FBK; ++tI) {
        const int cur = tI & 1;
        if (tI + 1 < Ktot / FBK) load_tile((tI + 1) * FBK);
#pragma unroll
        for (int kk = 0; kk < 2; ++kk) {
            bf16x8 af[4], bfr[2];
#pragma unroll
            for (int mf = 0; mf < 4; ++mf)
                af[mf] = *(const bf16x8*)&As[cur][wm * 64 + mf * 16 + lrow][kk * 32 + lkb];
#pragma unroll
            for (int nf = 0; nf < 2; ++nf)
                bfr[nf] = *(const bf16x8*)&Bs[cur][wn * 32 + nf * 16 + lrow][kk * 32 + lkb];
#pragma unroll
            for (int mf = 0; mf < 4; ++mf)
#pragma unroll
                for (int nf = 0; nf < 2; ++nf)
                    acc[mf][nf] = __builtin_amdgcn_mfma_f32_16x16x32_bf16(
                        af[mf], bfr[nf], acc[mf][nf], 0, 0, 0);
        }
        if (tI + 1 < Ktot / FBK) store_tile(cur ^ 1);
        __syncthreads();
    }
#pragma unroll
    for (int mf = 0; mf < 4; ++mf) {
        const int row0 = bm + wm * 64 + mf * 16 + ((lane >> 4) << 2);
#pragma unroll
        for (int nf = 0; nf < 2; ++nf) {
            const int col = bn + wn * 32 + nf * 16 + (lane & 15);
#pragma unroll
            for (int i = 0; i < 4; ++i)
                C[(size_t)(row0 + i) * Ntot + col] = acc[mf][nf][i];
        }
    }
}

extern "C" void kernel_launch(void* const* d_in, const int* in_sizes, int n_in,
                              void* d_out, int out_size, void* d_ws, size_t ws_size,
                              hipStream_t stream) {
    (void)in_sizes; (void)n_in; (void)out_size;
    const float* V  = (const float*)d_in[2];   // [B,S,F] = [M][K]
    const float* Vw = (const float*)d_in[5];   // [H,F,A]
    float* out      = (float*)d_out;           // [B,S,H,A] = [M][N]

    const size_t wtBytes = (size_t)Ntot * Ktot * sizeof(bf16_t);   // 2 MiB

    if (ws_size >= wtBytes) {
        bf16_t* Wt = (bf16_t*)d_ws;
        hipLaunchKernelGGL(prepass_w_kernel, dim3(256), dim3(256), 0, stream, Vw, Wt);
        hipLaunchKernelGGL(gemm_mixed_kernel, dim3((Mtot / 64) * (Ntot / 128)),
                           dim3(256), 0, stream, V, Wt, out);
    } else {
        hipLaunchKernelGGL(vproj_fused_kernel, dim3(256), dim3(512), 0, stream,
                           V, Vw, out);
    }
}